// Round 1
// baseline (1483.955 us; speedup 1.0000x reference)
//
#include <hip/hip_runtime.h>
#include <math.h>

typedef __attribute__((ext_vector_type(8))) short short8;
typedef __attribute__((ext_vector_type(4))) float f32x4;

__device__ __forceinline__ unsigned short f2bf(float f){
  union { unsigned int i; float f; } v; v.f = f;
  unsigned int u = v.i;
  return (unsigned short)((u + 0x7fffu + ((u >> 16) & 1u)) >> 16);
}

__device__ __forceinline__ void gload_lds16(const unsigned short* g, unsigned short* l){
  __builtin_amdgcn_global_load_lds(
      (const __attribute__((address_space(1))) void*)g,
      (__attribute__((address_space(3))) void*)l, 16, 0, 0);
}

// ---------------- weight convert + transpose: W[K][N] f32 -> Wt[N][K] bf16 ----
__global__ void wconv(const float* __restrict__ W, unsigned short* __restrict__ Wt,
                      int K, int N){
  long idx = (long)blockIdx.x * 256 + threadIdx.x;
  if (idx >= (long)K * N) return;
  int k = (int)(idx / N), n = (int)(idx % N);
  Wt[(long)n * K + k] = f2bf(W[idx]);
}

// ---------------- LayerNorm: x f32 [M][256] -> out bf16 [M][256] -------------
__global__ __launch_bounds__(256) void ln_kernel(
    const float* __restrict__ x, const float* __restrict__ g,
    const float* __restrict__ b, unsigned short* __restrict__ out){
  const int lane = threadIdx.x & 63;
  const int wv = threadIdx.x >> 6;
  const long row = (long)blockIdx.x * 4 + wv;
  const float4 xv = ((const float4*)(x + row * 256))[lane];
  float s  = xv.x + xv.y + xv.z + xv.w;
  float s2 = xv.x*xv.x + xv.y*xv.y + xv.z*xv.z + xv.w*xv.w;
  #pragma unroll
  for (int m = 1; m < 64; m <<= 1){
    s  += __shfl_xor(s,  m);
    s2 += __shfl_xor(s2, m);
  }
  float mu = s * (1.f/256.f);
  float rs = rsqrtf(s2 * (1.f/256.f) - mu*mu + 1e-5f);
  float4 gv = ((const float4*)g)[lane];
  float4 bv = ((const float4*)b)[lane];
  ushort4 o;
  o.x = f2bf((xv.x - mu)*rs*gv.x + bv.x);
  o.y = f2bf((xv.y - mu)*rs*gv.y + bv.y);
  o.z = f2bf((xv.z - mu)*rs*gv.z + bv.z);
  o.w = f2bf((xv.w - mu)*rs*gv.w + bv.w);
  ((ushort4*)(out + row * 256))[lane] = o;
}

// ---------------- GEMM: A[M][K] bf16 @ Wt[N][K] bf16 -> out [M][N] -----------
// MODE 0: out bf16 = acc + bias
// MODE 1: out bf16 = gelu(acc + bias)
// MODE 2: out f32  = acc + bias + res
template<int MODE>
__global__ __launch_bounds__(256, 2) void gemm_bt(
    const unsigned short* __restrict__ A,
    const unsigned short* __restrict__ Bt,
    const float* __restrict__ bias,
    const float* __restrict__ res,
    void* __restrict__ out,
    int N, int K){
  __shared__ unsigned short As[128*32];
  __shared__ unsigned short Bs[128*32];
  const int tid  = threadIdx.x;
  const int lane = tid & 63;
  const int wave = tid >> 6;
  const int wm = wave >> 1, wn = wave & 1;
  const long row0 = (long)blockIdx.y * 128;
  const int  col0 = blockIdx.x * 128;
  const int l15 = lane & 15, l4 = lane >> 4;

  f32x4 acc[4][4];
  #pragma unroll
  for (int i = 0; i < 4; ++i)
    #pragma unroll
    for (int j = 0; j < 4; ++j)
      acc[i][j] = (f32x4){0.f, 0.f, 0.f, 0.f};

  const int nk = K >> 5;
  for (int kt = 0; kt < nk; ++kt){
    #pragma unroll
    for (int i = 0; i < 2; ++i){
      int chunk = i * 256 + tid;
      int r = chunk >> 2, c = chunk & 3;
      gload_lds16(A  + (row0 + r) * K + kt*32 + c*8, &As[chunk*8]);
      gload_lds16(Bt + (long)(col0 + r) * K + kt*32 + c*8, &Bs[chunk*8]);
    }
    __syncthreads();
    short8 af[4], bfr[4];
    #pragma unroll
    for (int mi = 0; mi < 4; ++mi)
      af[mi] = *(const short8*)&As[(wm*64 + mi*16 + l15)*32 + 8*l4];
    #pragma unroll
    for (int ni = 0; ni < 4; ++ni)
      bfr[ni] = *(const short8*)&Bs[(wn*64 + ni*16 + l15)*32 + 8*l4];
    #pragma unroll
    for (int mi = 0; mi < 4; ++mi)
      #pragma unroll
      for (int ni = 0; ni < 4; ++ni)
        acc[mi][ni] = __builtin_amdgcn_mfma_f32_16x16x32_bf16(af[mi], bfr[ni], acc[mi][ni], 0, 0, 0);
    __syncthreads();
  }

  #pragma unroll
  for (int mi = 0; mi < 4; ++mi){
    #pragma unroll
    for (int ni = 0; ni < 4; ++ni){
      int colb = col0 + wn*64 + ni*16 + l15;
      float bv = bias[colb];
      #pragma unroll
      for (int j = 0; j < 4; ++j){
        long row = row0 + wm*64 + mi*16 + 4*l4 + j;
        long idx = row * N + colb;
        float v = acc[mi][ni][j] + bv;
        if (MODE == 0){
          ((unsigned short*)out)[idx] = f2bf(v);
        } else if (MODE == 1){
          v = 0.5f * v * (1.0f + erff(v * 0.70710678118654752f));
          ((unsigned short*)out)[idx] = f2bf(v);
        } else {
          ((float*)out)[idx] = v + res[idx];
        }
      }
    }
  }
}

// ---------------- Window attention: one block = one 8x8 window ---------------
// qkv bf16 [M][768] (3,8,32), bias_table f32 [225][8], ao bf16 [M][256]
__global__ __launch_bounds__(512, 1) void attn_kernel(
    const unsigned short* __restrict__ qkv,
    const float* __restrict__ bt,
    unsigned short* __restrict__ ao){
  __shared__ unsigned short P[8][64*64];
  const int lane = threadIdx.x & 63;
  const int h    = threadIdx.x >> 6;
  const int w = blockIdx.x;
  const int bidx = w >> 10, rem = w & 1023;
  const int wy = rem >> 5, wx = rem & 31;
  const long tok0 = (long)bidx * 65536 + (long)wy * 2048 + wx * 8;
  const int l15 = lane & 15, l4 = lane >> 4;

  // Q/K fragments (A-layout: row = l15, k contiguous 8 at 8*l4)
  short8 qf[4], kf[4];
  #pragma unroll
  for (int t = 0; t < 4; ++t){
    int n = t*16 + l15;
    long tok = tok0 + (n >> 3) * 256 + (n & 7);
    qf[t] = *(const short8*)(qkv + tok*768 +       h*32 + 8*l4);
    kf[t] = *(const short8*)(qkv + tok*768 + 256 + h*32 + 8*l4);
  }
  f32x4 s[4][4];
  #pragma unroll
  for (int i = 0; i < 4; ++i)
    #pragma unroll
    for (int j = 0; j < 4; ++j)
      s[i][j] = (f32x4){0.f, 0.f, 0.f, 0.f};
  #pragma unroll
  for (int mi = 0; mi < 4; ++mi)
    #pragma unroll
    for (int ni = 0; ni < 4; ++ni)
      s[mi][ni] = __builtin_amdgcn_mfma_f32_16x16x32_bf16(qf[mi], kf[ni], s[mi][ni], 0, 0, 0);

  const float scale = 0.17677669529663687f; // 1/sqrt(32)
  // scale + relative-position bias
  #pragma unroll
  for (int mi = 0; mi < 4; ++mi){
    #pragma unroll
    for (int j = 0; j < 4; ++j){
      int n = mi*16 + 4*l4 + j;
      int ny = n >> 3, nx = n & 7;
      #pragma unroll
      for (int ni = 0; ni < 4; ++ni){
        int m = ni*16 + l15;
        int db = (ny - (m >> 3) + 7) * 15 + (nx - (m & 7) + 7);
        s[mi][ni][j] = s[mi][ni][j] * scale + bt[db*8 + h];
      }
    }
  }
  // softmax over the 64 columns of each row; write P (bf16, XOR-swizzled)
  #pragma unroll
  for (int mi = 0; mi < 4; ++mi){
    #pragma unroll
    for (int j = 0; j < 4; ++j){
      float mx = fmaxf(fmaxf(s[mi][0][j], s[mi][1][j]), fmaxf(s[mi][2][j], s[mi][3][j]));
      mx = fmaxf(mx, __shfl_xor(mx, 1));
      mx = fmaxf(mx, __shfl_xor(mx, 2));
      mx = fmaxf(mx, __shfl_xor(mx, 4));
      mx = fmaxf(mx, __shfl_xor(mx, 8));
      float sm = 0.f;
      #pragma unroll
      for (int ni = 0; ni < 4; ++ni){
        float p = expf(s[mi][ni][j] - mx);
        s[mi][ni][j] = p;
        sm += p;
      }
      sm += __shfl_xor(sm, 1);
      sm += __shfl_xor(sm, 2);
      sm += __shfl_xor(sm, 4);
      sm += __shfl_xor(sm, 8);
      float inv = 1.f / sm;
      int n = mi*16 + 4*l4 + j;
      int swz = (n & 7) << 3;
      #pragma unroll
      for (int ni = 0; ni < 4; ++ni){
        int m = ni*16 + l15;
        P[h][n*64 + (m ^ swz)] = f2bf(s[mi][ni][j] * inv);
      }
    }
  }
  __syncthreads();

  // PV: out[64][32] = P[64][64] @ V[64][32]
  f32x4 o[4][2];
  #pragma unroll
  for (int i = 0; i < 4; ++i)
    #pragma unroll
    for (int j = 0; j < 2; ++j)
      o[i][j] = (f32x4){0.f, 0.f, 0.f, 0.f};
  #pragma unroll
  for (int kt = 0; kt < 2; ++kt){
    short8 vf[2];
    #pragma unroll
    for (int ni = 0; ni < 2; ++ni){
      union { unsigned short u[8]; short8 v; } tmp;
      #pragma unroll
      for (int i = 0; i < 8; ++i){
        int kk = kt*32 + 8*l4 + i;
        long tok = tok0 + (kk >> 3) * 256 + (kk & 7);
        tmp.u[i] = qkv[tok*768 + 512 + h*32 + ni*16 + l15];
      }
      vf[ni] = tmp.v;
    }
    #pragma unroll
    for (int mi = 0; mi < 4; ++mi){
      int r = mi*16 + l15;
      short8 pf = *(const short8*)&P[h][r*64 + ((kt*32 + 8*l4) ^ ((r & 7) << 3))];
      #pragma unroll
      for (int ni = 0; ni < 2; ++ni)
        o[mi][ni] = __builtin_amdgcn_mfma_f32_16x16x32_bf16(pf, vf[ni], o[mi][ni], 0, 0, 0);
    }
  }
  // write attention output
  #pragma unroll
  for (int mi = 0; mi < 4; ++mi){
    #pragma unroll
    for (int j = 0; j < 4; ++j){
      int n = mi*16 + 4*l4 + j;
      long tok = tok0 + (n >> 3) * 256 + (n & 7);
      #pragma unroll
      for (int ni = 0; ni < 2; ++ni)
        ao[tok*256 + h*32 + ni*16 + l15] = f2bf(o[mi][ni][j]);
    }
  }
}

extern "C" void kernel_launch(void* const* d_in, const int* in_sizes, int n_in,
                              void* d_out, int out_size, void* d_ws, size_t ws_size,
                              hipStream_t stream){
  const float* x      = (const float*)d_in[0];
  const float* ln1_g  = (const float*)d_in[1];
  const float* ln1_b  = (const float*)d_in[2];
  const float* qkv_w  = (const float*)d_in[3];
  const float* qkv_b  = (const float*)d_in[4];
  const float* proj_w = (const float*)d_in[5];
  const float* proj_b = (const float*)d_in[6];
  const float* btab   = (const float*)d_in[7];
  const float* ln2_g  = (const float*)d_in[8];
  const float* ln2_b  = (const float*)d_in[9];
  const float* fc1_w  = (const float*)d_in[10];
  const float* fc1_b  = (const float*)d_in[11];
  const float* fc2_w  = (const float*)d_in[12];
  const float* fc2_b  = (const float*)d_in[13];

  const long M = (long)in_sizes[0] / 256;  // 262144 tokens

  char* ws = (char*)d_ws;
  const size_t offA = 0;                    // 536,870,912 B: xn / ao / act (time-disjoint)
  const size_t offB = 536870912;            // 402,653,184 B: qkv, later hn
  const size_t offW = offB + 402653184;     // bf16 transposed weights
  unsigned short* xn  = (unsigned short*)(ws + offA);
  unsigned short* ao  = (unsigned short*)(ws + offA);
  unsigned short* act = (unsigned short*)(ws + offA);
  unsigned short* qkv = (unsigned short*)(ws + offB);
  unsigned short* hn  = (unsigned short*)(ws + offB);
  unsigned short* wq  = (unsigned short*)(ws + offW);
  unsigned short* wp  = wq + 256*768;
  unsigned short* w1  = wp + 256*256;
  unsigned short* w2  = w1 + 256*1024;
  float* outf = (float*)d_out;

  // weights -> bf16 transposed
  wconv<<<(256*768 + 255)/256, 256, 0, stream>>>(qkv_w, wq, 256, 768);
  wconv<<<(256*256 + 255)/256, 256, 0, stream>>>(proj_w, wp, 256, 256);
  wconv<<<(256*1024 + 255)/256, 256, 0, stream>>>(fc1_w, w1, 256, 1024);
  wconv<<<(1024*256 + 255)/256, 256, 0, stream>>>(fc2_w, w2, 1024, 256);

  // LN1
  ln_kernel<<<M/4, 256, 0, stream>>>(x, ln1_g, ln1_b, xn);
  // QKV
  gemm_bt<0><<<dim3(768/128, M/128), 256, 0, stream>>>(xn, wq, qkv_b, nullptr, qkv, 768, 256);
  // window attention
  attn_kernel<<<M/64, 512, 0, stream>>>(qkv, btab, ao);
  // proj + residual(x) -> h (f32, in d_out)
  gemm_bt<2><<<dim3(256/128, M/128), 256, 0, stream>>>(ao, wp, proj_b, x, outf, 256, 256);
  // LN2
  ln_kernel<<<M/4, 256, 0, stream>>>(outf, ln2_g, ln2_b, hn);
  // FC1 + GELU
  gemm_bt<1><<<dim3(1024/128, M/128), 256, 0, stream>>>(hn, w1, fc1_b, nullptr, act, 1024, 256);
  // FC2 + residual(h) -> out
  gemm_bt<2><<<dim3(256/128, M/128), 256, 0, stream>>>(act, w2, fc2_b, outf, outf, 256, 1024);
}